// Round 1
// baseline (435.502 us; speedup 1.0000x reference)
//
#include <hip/hip_runtime.h>
#include <stdint.h>

#define E_DIM 512
#define NM 24
#define NC 48      // NM * 2 (re/im interleaved)
#define NCOL 96    // q(48) + k(48)
#define B_DIM 16
#define H_DIM 4096
#define NROWS (B_DIM * H_DIM)

// ---------- K1: combined DFT projection matrices C[512][96], bias d[96] ----------
// C[e][mat*48+2j+p] = sum_o W[o][e] * {cos,-sin}(2*pi*f_j*o/512)
__global__ __launch_bounds__(128)
void k_buildC(const float* __restrict__ Wq, const float* __restrict__ Wk,
              const float* __restrict__ bq, const float* __restrict__ bk,
              const int* __restrict__ idxq,
              float* __restrict__ C, float* __restrict__ dvec) {
  __shared__ float twc[E_DIM], tws[E_DIM];
  __shared__ int fj[NM];
  const int t = threadIdx.x;
  for (int i = t; i < E_DIM; i += 128) {
    float s, c;
    sincospif((float)i * (1.0f / 256.0f), &s, &c);   // angle = 2*pi*i/512
    twc[i] = c; tws[i] = s;
  }
  if (t < NM) fj[t] = idxq[t];
  __syncthreads();
  const int e = blockIdx.x;            // 0..511 = W column, 512 = bias row
  if (t >= NCOL) return;
  const int mat = t / NC;              // 0 = q, 1 = k
  const int c = t - mat * NC;
  const int j = c >> 1, p = c & 1;
  const int f = fj[j];
  float acc = 0.0f;
  if (e < E_DIM) {
    const float* __restrict__ W = mat ? Wk : Wq;
    for (int o = 0; o < E_DIM; ++o) {
      const float w = W[o * E_DIM + e];
      const int tt = (f * o) & (E_DIM - 1);
      acc = fmaf(w, p ? -tws[tt] : twc[tt], acc);
    }
    C[e * NCOL + t] = acc;
  } else {
    const float* __restrict__ bv = mat ? bk : bq;
    for (int o = 0; o < E_DIM; ++o) {
      const int tt = (f * o) & (E_DIM - 1);
      acc = fmaf(bv[o], p ? -tws[tt] : twc[tt], acc);
    }
    dvec[t] = acc;
  }
}

// ---------- K1b: irfft synthesis matrix M[48][512] ----------
__global__ __launch_bounds__(256)
void k_buildM(const int* __restrict__ idxq, float* __restrict__ M) {
  const int gid = blockIdx.x * 256 + threadIdx.x;
  if (gid >= NC * E_DIM) return;
  const int c = gid >> 9;
  const int e = gid & (E_DIM - 1);
  const int j = c >> 1, p = c & 1;
  const int f = idxq[j];
  const float w = (f == 0 ? 1.0f : 2.0f) * (1.0f / (float)E_DIM);
  float s, cc;
  sincospif((float)((f * e) & (E_DIM - 1)) * (1.0f / 256.0f), &s, &cc);
  M[c * E_DIM + e] = p ? (-w * s) : (w * cc);
}

// ---------- K2: G[65536][96] = x[65536][512] @ C[512][96] + d ----------
#define GBM 128
#define GBK 32
__global__ __launch_bounds__(512)
void k_gemmG(const float* __restrict__ x, const float* __restrict__ C,
             const float* __restrict__ dvec, float* __restrict__ G) {
  __shared__ __align__(16) float xs[GBK][GBM + 4];   // [32][132], transposed tile
  __shared__ __align__(16) float cs[GBK * NCOL];     // [32][96]
  __shared__ float dsh[NCOL];
  const int t = threadIdx.x;
  const int ri = t >> 4;    // 0..31 -> 4 rows each
  const int ci = t & 15;    // 0..15 -> 6 cols each
  const int row0 = blockIdx.x * GBM;
  if (t < NCOL) dsh[t] = dvec[t];
  float acc[4][6];
#pragma unroll
  for (int a = 0; a < 4; ++a)
#pragma unroll
    for (int b = 0; b < 6; ++b) acc[a][b] = 0.0f;

  for (int k0 = 0; k0 < E_DIM; k0 += GBK) {
    __syncthreads();
#pragma unroll
    for (int it = 0; it < 2; ++it) {            // x tile: 128 rows x 32 k
      const int idx = t + it * 512;
      const int row = idx >> 3, kc = idx & 7;
      const float4 v = *(const float4*)&x[(row0 + row) * E_DIM + k0 + kc * 4];
      xs[kc * 4 + 0][row] = v.x;
      xs[kc * 4 + 1][row] = v.y;
      xs[kc * 4 + 2][row] = v.z;
      xs[kc * 4 + 3][row] = v.w;
    }
#pragma unroll
    for (int it = 0; it < 2; ++it) {            // C tile: 32 x 96 (contiguous)
      const int idx = t + it * 512;
      if (idx < (GBK * NCOL) / 4)
        *(float4*)&cs[idx * 4] = *(const float4*)&C[k0 * NCOL + idx * 4];
    }
    __syncthreads();
#pragma unroll 8
    for (int kk = 0; kk < GBK; ++kk) {
      const float4 xv = *(const float4*)&xs[kk][ri * 4];
      const float2 c0 = *(const float2*)&cs[kk * NCOL + ci * 6 + 0];
      const float2 c1 = *(const float2*)&cs[kk * NCOL + ci * 6 + 2];
      const float2 c2 = *(const float2*)&cs[kk * NCOL + ci * 6 + 4];
      const float xr[4] = {xv.x, xv.y, xv.z, xv.w};
      const float cv[6] = {c0.x, c0.y, c1.x, c1.y, c2.x, c2.y};
#pragma unroll
      for (int a = 0; a < 4; ++a)
#pragma unroll
        for (int b = 0; b < 6; ++b)
          acc[a][b] = fmaf(xr[a], cv[b], acc[a][b]);
    }
  }
#pragma unroll
  for (int a = 0; a < 4; ++a) {
    const int row = row0 + ri * 4 + a;
#pragma unroll
    for (int b = 0; b < 6; b += 2) {
      float2 v;
      v.x = acc[a][b]     + dsh[ci * 6 + b];
      v.y = acc[a][b + 1] + dsh[ci * 6 + b + 1];
      *(float2*)&G[row * NCOL + ci * 6 + b] = v;
    }
  }
}

// ---------- K3a: partial S over h-chunks: Sp[b][hc][24][24]{re,im} ----------
__global__ __launch_bounds__(576)
void k_spart(const float* __restrict__ G, float* __restrict__ Sp) {
  const int t = threadIdx.x;           // 0..575 = (x,y)
  const int xx = t / NM, yy = t - xx * NM;
  const int bc = blockIdx.x;           // b*32 + hc
  const int b = bc >> 5, hc = bc & 31;
  const int r0 = b * H_DIM + hc * 128;
  float sre = 0.0f, sim = 0.0f;
  for (int h = 0; h < 128; ++h) {
    const float* __restrict__ g = &G[(r0 + h) * NCOL];
    const float2 q = *(const float2*)&g[2 * xx];
    const float2 k = *(const float2*)&g[NC + 2 * yy];
    sre += q.x * k.x - q.y * k.y;      // complex product, no conjugation
    sim += q.x * k.y + q.y * k.x;
  }
  ((float2*)Sp)[bc * 576 + t] = make_float2(sre, sim);
}

// ---------- K3b: reduce chunks, |.|, row softmax -> att[b][24][24] ----------
__global__ __launch_bounds__(576)
void k_att(const float* __restrict__ Sp, float* __restrict__ att) {
  __shared__ float mag[576];
  __shared__ float ex[576];
  const int t = threadIdx.x;
  const int b = blockIdx.x;
  float sre = 0.0f, sim = 0.0f;
  const float2* in2 = (const float2*)Sp;
  for (int hc = 0; hc < 32; ++hc) {
    const float2 v = in2[(b * 32 + hc) * 576 + t];
    sre += v.x; sim += v.y;
  }
  mag[t] = sqrtf(sre * sre + sim * sim);
  __syncthreads();
  const int xx = t / NM;
  float m = -1e30f;
  for (int k = 0; k < NM; ++k) m = fmaxf(m, mag[xx * NM + k]);
  const float e = expf(mag[t] - m);
  ex[t] = e;
  __syncthreads();
  float s = 0.0f;
  for (int k = 0; k < NM; ++k) s += ex[xx * NM + k];
  att[b * 576 + t] = e / s;
}

// ---------- K4: Z[row][48] = att[b] applied to K-spectrum ----------
__global__ __launch_bounds__(256)
void k_z(const float* __restrict__ G, const float* __restrict__ att,
         float* __restrict__ Z) {
  __shared__ float at[576];
  const int t = threadIdx.x;
  const int row = blockIdx.x * 256 + t;
  const int b = blockIdx.x >> 4;       // 4096 rows per batch / 256 rows per block
  for (int i = t; i < 576; i += 256) at[i] = att[b * 576 + i];
  __syncthreads();
  float gk[NC];
#pragma unroll
  for (int i = 0; i < NC / 4; ++i) {
    const float4 v = *(const float4*)&G[row * NCOL + NC + i * 4];
    gk[i * 4 + 0] = v.x; gk[i * 4 + 1] = v.y; gk[i * 4 + 2] = v.z; gk[i * 4 + 3] = v.w;
  }
  float z[NC];
#pragma unroll
  for (int xx = 0; xx < NM; ++xx) {
    float zr = 0.0f, zi = 0.0f;
#pragma unroll
    for (int y = 0; y < NM; ++y) {
      const float a = at[xx * NM + y];
      zr = fmaf(a, gk[2 * y], zr);
      zi = fmaf(a, gk[2 * y + 1], zi);
    }
    z[2 * xx] = zr; z[2 * xx + 1] = zi;
  }
#pragma unroll
  for (int i = 0; i < NC / 4; ++i) {
    float4 v;
    v.x = z[i * 4]; v.y = z[i * 4 + 1]; v.z = z[i * 4 + 2]; v.w = z[i * 4 + 3];
    *(float4*)&Z[row * NC + i * 4] = v;
  }
}

// ---------- K5: out[65536][512] = Z[65536][48] @ M[48][512] ----------
#define OBM 128
#define OBN 128
__global__ __launch_bounds__(256)
void k_out(const float* __restrict__ Z, const float* __restrict__ M,
           float* __restrict__ out) {
  __shared__ __align__(16) float zs[NC][OBM + 4];
  __shared__ __align__(16) float ms[NC * OBN];
  const int t = threadIdx.x;
  const int ri = t >> 4, ci = t & 15;       // 8 rows x 8 cols per thread
  const int row0 = (blockIdx.x >> 2) * OBM;
  const int e0 = (blockIdx.x & 3) * OBN;
#pragma unroll
  for (int it = 0; it < 6; ++it) {          // Z tile 128x48
    const int idx = t + it * 256;
    const int row = idx / 12, kc = idx - row * 12;
    const float4 v = *(const float4*)&Z[(row0 + row) * NC + kc * 4];
    zs[kc * 4 + 0][row] = v.x;
    zs[kc * 4 + 1][row] = v.y;
    zs[kc * 4 + 2][row] = v.z;
    zs[kc * 4 + 3][row] = v.w;
  }
#pragma unroll
  for (int it = 0; it < 6; ++it) {          // M tile 48x128
    const int idx = t + it * 256;
    const int k = idx >> 5, ec = idx & 31;
    *(float4*)&ms[k * OBN + ec * 4] = *(const float4*)&M[k * E_DIM + e0 + ec * 4];
  }
  __syncthreads();
  float acc[8][8];
#pragma unroll
  for (int a = 0; a < 8; ++a)
#pragma unroll
    for (int b = 0; b < 8; ++b) acc[a][b] = 0.0f;
#pragma unroll 4
  for (int k = 0; k < NC; ++k) {
    const float4 za = *(const float4*)&zs[k][ri * 8];
    const float4 zb = *(const float4*)&zs[k][ri * 8 + 4];
    const float4 ma = *(const float4*)&ms[k * OBN + ci * 8];
    const float4 mb = *(const float4*)&ms[k * OBN + ci * 8 + 4];
    const float zr[8] = {za.x, za.y, za.z, za.w, zb.x, zb.y, zb.z, zb.w};
    const float mr[8] = {ma.x, ma.y, ma.z, ma.w, mb.x, mb.y, mb.z, mb.w};
#pragma unroll
    for (int a = 0; a < 8; ++a)
#pragma unroll
      for (int b = 0; b < 8; ++b)
        acc[a][b] = fmaf(zr[a], mr[b], acc[a][b]);
  }
#pragma unroll
  for (int a = 0; a < 8; ++a) {
    const int row = row0 + ri * 8 + a;
    float4 v0, v1;
    v0.x = acc[a][0]; v0.y = acc[a][1]; v0.z = acc[a][2]; v0.w = acc[a][3];
    v1.x = acc[a][4]; v1.y = acc[a][5]; v1.z = acc[a][6]; v1.w = acc[a][7];
    *(float4*)&out[row * E_DIM + e0 + ci * 8] = v0;
    *(float4*)&out[row * E_DIM + e0 + ci * 8 + 4] = v1;
  }
}

extern "C" void kernel_launch(void* const* d_in, const int* in_sizes, int n_in,
                              void* d_out, int out_size, void* d_ws, size_t ws_size,
                              hipStream_t stream) {
  const float* x  = (const float*)d_in[0];
  const float* Wq = (const float*)d_in[1];
  const float* bq = (const float*)d_in[2];
  const float* Wk = (const float*)d_in[3];
  const float* bk = (const float*)d_in[4];
  // d_in[5] (Wv), d_in[6] (bv): dead code in reference, never read
  const int* idxq = (const int*)d_in[7];
  float* out = (float*)d_out;
  float* ws = (float*)d_ws;

  // ws layout (floats): C 49152 | d 128 | M 24576 | att 9216 | Sp 589824 | Z 3145728
  float* C   = ws;
  float* dv  = ws + 49152;
  float* M   = ws + 49280;
  float* att = ws + 73856;
  float* Sp  = ws + 83072;
  float* Z   = ws + 672896;          // total ~14.6 MB of ws
  float* G   = out;                  // park G[65536][96] in d_out; dead before k_out writes

  k_buildC<<<E_DIM + 1, 128, 0, stream>>>(Wq, Wk, bq, bk, idxq, C, dv);
  k_buildM<<<(NC * E_DIM + 255) / 256, 256, 0, stream>>>(idxq, M);
  k_gemmG<<<NROWS / GBM, 512, 0, stream>>>(x, C, dv, G);
  k_spart<<<B_DIM * 32, 576, 0, stream>>>(G, Sp);
  k_att<<<B_DIM, 576, 0, stream>>>(Sp, att);
  k_z<<<NROWS / 256, 256, 0, stream>>>(G, att, Z);
  k_out<<<(NROWS / OBM) * (E_DIM / OBN), 256, 0, stream>>>(Z, M, out);
}